// Round 8
// baseline (240.900 us; speedup 1.0000x reference)
//
#include <hip/hip_runtime.h>
#include <hip/hip_fp16.h>
#include <math.h>

#define HH 256
#define WW 256
#define CTOT 256
#define HW (HH * WW)
#define NBIN 49

typedef __attribute__((ext_vector_type(8))) _Float16 half8;
typedef __attribute__((ext_vector_type(4))) float fvec4;

// ---------- pass 0: per-RoI param table (12 floats = 3 float4 per roi) ----------
// [0]=cx [1]=cy [2]=rwv [3]=rhv | [4]=cos [5]=sin [6]=r_var [7]=l_var | [8]=ind [9]=b*32 [10,11]=pad
__global__ __launch_bounds__(256) void roi_table_kernel(
    const float* __restrict__ rois, float* __restrict__ tbl, int n_rois)
{
    const int n = blockIdx.x * 256 + threadIdx.x;
    if (n >= n_rois) return;
    const float* r = rois + n * 6;
    const float theta = r[5];
    const float ind_f = (theta * 8.0f) / 6.28318530717958647692f;
    const int   ind0  = (int)floorf(ind_f);
    float* o = tbl + n * 12;
    o[0] = r[1] * 0.25f;
    o[1] = r[2] * 0.25f;
    o[2] = fmaxf(r[3] * 0.25f, 1.0f);
    o[3] = fmaxf(r[4] * 0.25f, 1.0f);
    o[4] = cosf(theta);                    // CLOCKWISE=false
    o[5] = sinf(theta);
    o[6] = 1.0f - (ind_f - (float)ind0);   // r_var
    o[7] = ind_f - (float)ind0;            // l_var
    o[8] = (float)(((ind0 % 8) + 8) % 8);  // ind
    o[9] = (float)(((int)r[0]) * 32);      // b*32
    o[10] = 0.0f; o[11] = 0.0f;
}

// ---------- pass 1: (B,256,H,W) f32 -> (B,32,H,W,8) f16 orientation-interleaved ----------
__global__ __launch_bounds__(256) void convert_kernel_v2(
    const float* __restrict__ feats, half8* __restrict__ wsf, int total4 /* B*32*HW/4 */)
{
    const int g = blockIdx.x * 256 + threadIdx.x;
    if (g >= total4) return;
    const int pix = (g & 16383) << 2;        // HW/4 = 16384
    const int bc  = g >> 14;                 // b*32 + c
    const float* src = feats + ((size_t)bc * 8) * HW + pix;
    fvec4 v[8];
    #pragma unroll
    for (int o = 0; o < 8; ++o)
        v[o] = __builtin_nontemporal_load((const fvec4*)(src + (size_t)o * HW));
    half8* dst = wsf + (size_t)bc * HW + pix;
    #pragma unroll
    for (int j = 0; j < 4; ++j) {
        half8 h;
        h[0] = (_Float16)v[0][j]; h[1] = (_Float16)v[1][j];
        h[2] = (_Float16)v[2][j]; h[3] = (_Float16)v[3][j];
        h[4] = (_Float16)v[4][j]; h[5] = (_Float16)v[5][j];
        h[6] = (_Float16)v[6][j]; h[7] = (_Float16)v[7][j];
        dst[j] = h;
    }
}

// ---------- pass 2: thread = (cg, roi, bin, sample-row gy); 8 independent 16B gathers ----------
__global__ __launch_bounds__(256) void riroi_pool_f16_v4(
    const half8* __restrict__ wsf,     // (B, 32, HW) of half8
    const float* __restrict__ tbl,     // roi table
    float* __restrict__ out,           // (n_rois, 256, 7, 7)
    int per_cg2)                       // n_rois * 49 * 2
{
    const int h = blockIdx.x * 256 + threadIdx.x;
    if (h >= per_cg2) return;
    const int cg  = blockIdx.y;        // channel group 0..31
    const int sh  = h & 1;             // sample row gy
    const int t   = h >> 1;
    const int n   = t / NBIN;
    const int bin = t - n * NBIN;
    const int ph  = bin / 7;
    const int pw  = bin - ph * 7;

    const fvec4 p0 = *(const fvec4*)(tbl + n * 12);
    const fvec4 p1 = *(const fvec4*)(tbl + n * 12 + 4);
    const fvec4 p2 = *(const fvec4*)(tbl + n * 12 + 8);
    const float cx = p0[0], cy = p0[1], rwv = p0[2], rhv = p0[3];
    const float cos_t = p1[0], sin_t = p1[1], r_var = p1[2], l_var = p1[3];
    const int   ind = (int)p2[0];
    const int   b32 = (int)p2[1];
    const float bin_h = rhv * (1.0f / 7.0f);
    const float bin_w = rwv * (1.0f / 7.0f);

    // ---- geometry for 2 samples (gy=sh, gx=0,1) ----
    int   off0[2], off1[2];
    float w00[2], w01[2], w10[2], w11[2];
    const float yy = -rhv * 0.5f + ((float)ph + ((float)sh + 0.5f) * 0.5f) * bin_h;
    #pragma unroll
    for (int j = 0; j < 2; ++j) {
        const float xx = -rwv * 0.5f + ((float)pw + ((float)j + 0.5f) * 0.5f) * bin_w;
        const float y  = yy * cos_t - xx * sin_t + cy;
        const float x  = yy * sin_t + xx * cos_t + cx;
        const float valid =
            (y >= -1.0f && y <= 256.0f && x >= -1.0f && x <= 256.0f) ? 1.0f : 0.0f;
        const float yc = fmaxf(y, 0.0f);
        const float xc = fmaxf(x, 0.0f);
        const int y0 = min((int)floorf(yc), HH - 1);
        const int x0 = min((int)floorf(xc), WW - 1);
        const int y1 = min(y0 + 1, HH - 1);
        const float ly = (y0 >= HH - 1) ? 0.0f : (yc - (float)y0);
        const float lx = (x0 >= WW - 1) ? 0.0f : (xc - (float)x0);
        const float hy = 1.0f - ly, hx = 1.0f - lx;
        const float sc = 0.25f * valid;
        const int   xb = min(x0, WW - 2);          // pair base (xb, xb+1) in-bounds
        const float c0 = (x0 < WW - 1) ? hx : 0.0f;   // x0==255 -> value in .y slot
        const float c1 = (x0 < WW - 1) ? lx : hx;
        w00[j] = hy * sc * c0;
        w01[j] = hy * sc * c1;
        w10[j] = ly * sc * c0;
        w11[j] = ly * sc * c1;
        off0[j] = (y0 << 8) + xb;
        off1[j] = (y1 << 8) + xb;
    }

    const half8* base = wsf + (size_t)(b32 + cg) * HW;

    // 8 independent 16B loads
    const half8 q0 = base[off0[0]];
    const half8 q1 = base[off0[0] + 1];
    const half8 q2 = base[off1[0]];
    const half8 q3 = base[off1[0] + 1];
    const half8 q4 = base[off0[1]];
    const half8 q5 = base[off0[1] + 1];
    const half8 q6 = base[off1[1]];
    const half8 q7 = base[off1[1] + 1];

    float acc[8];
    #pragma unroll
    for (int o = 0; o < 8; ++o)
        acc[o] = w00[0] * (float)q0[o] + w01[0] * (float)q1[o]
               + w10[0] * (float)q2[o] + w11[0] * (float)q3[o]
               + w00[1] * (float)q4[o] + w01[1] * (float)q5[o]
               + w10[1] * (float)q6[o] + w11[1] * (float)q7[o];

    // combine the two sample-rows (lane pairs co-active)
    #pragma unroll
    for (int o = 0; o < 8; ++o)
        acc[o] += __shfl_xor(acc[o], 1, 64);

    // ---- orientation mix; even lane stores k=0..3, odd k=4..7 ----
    float* obase = out + ((size_t)n * CTOT + (size_t)(cg * 8)) * NBIN + bin;
    if (sh == 0) {
        #pragma unroll
        for (int k = 0; k < 4; ++k)
            __builtin_nontemporal_store(r_var * acc[k] + l_var * acc[k + 1],
                                        obase + (((k + ind) & 7) * NBIN));
    } else {
        #pragma unroll
        for (int k = 4; k < 8; ++k)
            __builtin_nontemporal_store(r_var * acc[k] + l_var * acc[(k + 1) & 7],
                                        obase + (((k + ind) & 7) * NBIN));
    }
}

// ---------- fallback if workspace too small ----------
__global__ __launch_bounds__(256) void riroi_rotated_fallback(
    const float* __restrict__ feats, const float* __restrict__ rois,
    float* __restrict__ out, int total)
{
    const int g = blockIdx.x * 256 + threadIdx.x;
    if (g >= total) return;
    const int wpr = 32 * NBIN;
    const int n   = g / wpr;
    const int rem = g - n * wpr;
    const int cg  = rem / NBIN;
    const int bin = rem - cg * NBIN;
    const int ph  = bin / 7;
    const int pw  = bin - ph * 7;
    const float* r = rois + n * 6;
    const int   b     = (int)r[0];
    const float cx    = r[1] * 0.25f;
    const float cy    = r[2] * 0.25f;
    const float rwv   = fmaxf(r[3] * 0.25f, 1.0f);
    const float rhv   = fmaxf(r[4] * 0.25f, 1.0f);
    const float theta = r[5];
    const float bin_h = rhv * (1.0f / 7.0f);
    const float bin_w = rwv * (1.0f / 7.0f);
    const float ind_f = (theta * 8.0f) / 6.28318530717958647692f;
    const int   ind0  = (int)floorf(ind_f);
    const float l_var = ind_f - (float)ind0;
    const float r_var = 1.0f - l_var;
    const int   ind   = ((ind0 % 8) + 8) % 8;
    const float cos_t = cosf(theta);
    const float sin_t = sinf(theta);
    int   off0[4], off1[4];
    float rw0[4], rw1[4], cw0[4], cw1[4];
    #pragma unroll
    for (int s = 0; s < 4; ++s) {
        const int gy = s >> 1, gx = s & 1;
        const float yy = -rhv * 0.5f + ((float)ph + ((float)gy + 0.5f) * 0.5f) * bin_h;
        const float xx = -rwv * 0.5f + ((float)pw + ((float)gx + 0.5f) * 0.5f) * bin_w;
        const float y  = yy * cos_t - xx * sin_t + cy;
        const float x  = yy * sin_t + xx * cos_t + cx;
        const float valid =
            (y >= -1.0f && y <= 256.0f && x >= -1.0f && x <= 256.0f) ? 1.0f : 0.0f;
        const float yc = fmaxf(y, 0.0f);
        const float xc = fmaxf(x, 0.0f);
        const int y0 = min((int)floorf(yc), HH - 1);
        const int x0 = min((int)floorf(xc), WW - 1);
        const int y1 = min(y0 + 1, HH - 1);
        const float ly = (y0 >= HH - 1) ? 0.0f : (yc - (float)y0);
        const float lx = (x0 >= WW - 1) ? 0.0f : (xc - (float)x0);
        const float hy = 1.0f - ly, hx = 1.0f - lx;
        const float sc = 0.25f * valid;
        const int   xb = min(x0, WW - 2);
        cw0[s]  = (x0 < WW - 1) ? hx : 0.0f;
        cw1[s]  = (x0 < WW - 1) ? lx : hx;
        rw0[s]  = hy * sc;
        rw1[s]  = ly * sc;
        off0[s] = (y0 << 8) + xb;
        off1[s] = (y1 << 8) + xb;
    }
    const float* gbase = feats + (size_t)b * (CTOT * HW) + (size_t)(cg * 8) * HW;
    float acc[8];
    #pragma unroll
    for (int o = 0; o < 8; o += 2) {
        const float* pA = gbase + (size_t)o * HW;
        const float* pB = pA + HW;
        float2 q[16];
        #pragma unroll
        for (int s = 0; s < 4; ++s) {
            q[s * 4 + 0] = *(const float2*)(pA + off0[s]);
            q[s * 4 + 1] = *(const float2*)(pA + off1[s]);
            q[s * 4 + 2] = *(const float2*)(pB + off0[s]);
            q[s * 4 + 3] = *(const float2*)(pB + off1[s]);
        }
        float a0 = 0.0f, a1 = 0.0f;
        #pragma unroll
        for (int s = 0; s < 4; ++s) {
            a0 += rw0[s] * (cw0[s] * q[s * 4 + 0].x + cw1[s] * q[s * 4 + 0].y)
                + rw1[s] * (cw0[s] * q[s * 4 + 1].x + cw1[s] * q[s * 4 + 1].y);
            a1 += rw0[s] * (cw0[s] * q[s * 4 + 2].x + cw1[s] * q[s * 4 + 2].y)
                + rw1[s] * (cw0[s] * q[s * 4 + 3].x + cw1[s] * q[s * 4 + 3].y);
        }
        acc[o] = a0; acc[o + 1] = a1;
    }
    float* obase = out + ((size_t)n * CTOT + (size_t)(cg * 8)) * NBIN + bin;
    #pragma unroll
    for (int s = 0; s < 8; ++s) {
        const int o_out = (s + ind) & 7;
        __builtin_nontemporal_store(r_var * acc[s] + l_var * acc[(s + 1) & 7],
                                    obase + o_out * NBIN);
    }
}

extern "C" void kernel_launch(void* const* d_in, const int* in_sizes, int n_in,
                              void* d_out, int out_size, void* d_ws, size_t ws_size,
                              hipStream_t stream) {
    const float* feats = (const float*)d_in[0];
    const float* rois  = (const float*)d_in[1];
    float* out = (float*)d_out;
    const int n_rois = in_sizes[1] / 6;
    const int B      = in_sizes[0] / (CTOT * HW);
    const size_t img_bytes = (size_t)B * 32 * HW * sizeof(half8);
    const size_t tbl_bytes = (size_t)n_rois * 12 * sizeof(float);

    if (ws_size >= img_bytes + tbl_bytes) {
        half8* wsf = (half8*)d_ws;
        float* tbl = (float*)((char*)d_ws + img_bytes);
        roi_table_kernel<<<(n_rois + 255) / 256, 256, 0, stream>>>(rois, tbl, n_rois);
        const int tc4 = B * 32 * HW / 4;
        convert_kernel_v2<<<(tc4 + 255) / 256, 256, 0, stream>>>(feats, wsf, tc4);
        const int per_cg2 = n_rois * NBIN * 2;
        dim3 grid((per_cg2 + 255) / 256, 32);
        riroi_pool_f16_v4<<<grid, 256, 0, stream>>>(wsf, tbl, out, per_cg2);
    } else {
        const int total = n_rois * 32 * NBIN;
        riroi_rotated_fallback<<<(total + 255) / 256, 256, 0, stream>>>(feats, rois, out, total);
    }
}